// Round 10
// baseline (599.582 us; speedup 1.0000x reference)
//
#include <hip/hip_runtime.h>

// MOE transformer block — v3.1: 256²/8-wave 2-phase counted-vmcnt GEMM (QKV, FFN1)
// with corrected final-iteration vmcnt(0) drain; m97-style 128-tile GEMM for
// o-proj/FFN2; MFMA flash attention; pre-transposed bf16 weights.

typedef unsigned int  u32;
typedef unsigned short u16;
typedef short v8s __attribute__((ext_vector_type(8)));   // 8 x bf16 fragment
typedef float v4f __attribute__((ext_vector_type(4)));   // 4 x f32 accum

#define SEQ  2048
#define DIM_ 1024
#define EPS_ 1e-5f

__device__ __forceinline__ u16 f2bf(float f) {
    __bf16 h = (__bf16)f;
    return __builtin_bit_cast(u16, h);
}

__device__ __forceinline__ void gload16(const void* g, void* l) {
    __builtin_amdgcn_global_load_lds((const __attribute__((address_space(1))) u32*)g,
                                     (__attribute__((address_space(3))) u32*)l, 16, 0, 0);
}

// ------------------------------------------------- weight transpose+cast
template<bool SEP>
__global__ __launch_bounds__(256) void conv_t(const float* __restrict__ s0,
                                              const float* __restrict__ s1,
                                              const float* __restrict__ s2,
                                              const float* __restrict__ s3,
                                              u16* __restrict__ dst, int K, int N) {
    __shared__ __attribute__((aligned(16))) u16 Ts[64][72];
    int tid = threadIdx.x;
    int z = blockIdx.z;
    const float* src = SEP ? (z == 0 ? s0 : z == 1 ? s1 : z == 2 ? s2 : s3)
                           : s0 + (size_t)z * K * N;
    u16* d = dst + (size_t)z * K * N;
    int k0 = blockIdx.y * 64, n0 = blockIdx.x * 64;
    int tk = tid >> 4, tn = tid & 15;

    u16 t[4][4];
    #pragma unroll
    for (int r = 0; r < 4; r++) {
        float4 L = *(const float4*)&src[(size_t)(k0 + tk * 4 + r) * N + n0 + tn * 4];
        t[r][0] = f2bf(L.x); t[r][1] = f2bf(L.y); t[r][2] = f2bf(L.z); t[r][3] = f2bf(L.w);
    }
    #pragma unroll
    for (int c = 0; c < 4; c++) {
        ushort4 q4 = { t[0][c], t[1][c], t[2][c], t[3][c] };
        *(ushort4*)&Ts[tn * 4 + c][tk * 4] = q4;
    }
    __syncthreads();
    #pragma unroll
    for (int i = 0; i < 2; i++) {
        int id = tid + i * 256;
        int row = id >> 3, ch = id & 7;
        v8s val = *(const v8s*)&Ts[row][ch * 8];
        *(v8s*)&d[(size_t)(n0 + row) * K + k0 + ch * 8] = val;
    }
}

// ---------------------------------------------------------------- LayerNorm
__global__ __launch_bounds__(256) void ln_kernel(const float* __restrict__ x,
                                                 const float* __restrict__ g,
                                                 const float* __restrict__ b,
                                                 u16* __restrict__ out) {
    int row = blockIdx.x;
    int t = threadIdx.x;
    const float4* xr = (const float4*)(x + (size_t)row * DIM_);
    float4 v = xr[t];
    float s  = v.x + v.y + v.z + v.w;
    float ss = v.x*v.x + v.y*v.y + v.z*v.z + v.w*v.w;
    #pragma unroll
    for (int off = 32; off > 0; off >>= 1) {
        s  += __shfl_down(s, off);
        ss += __shfl_down(ss, off);
    }
    __shared__ float red[8];
    if ((t & 63) == 0) { red[t >> 6] = s; red[4 + (t >> 6)] = ss; }
    __syncthreads();
    s  = red[0] + red[1] + red[2] + red[3];
    ss = red[4] + red[5] + red[6] + red[7];
    float mean = s * (1.0f / DIM_);
    float var  = ss * (1.0f / DIM_) - mean * mean;
    float rstd = rsqrtf(var + EPS_);
    float4 gv = ((const float4*)g)[t];
    float4 bv = ((const float4*)b)[t];
    ushort4 ov;
    ov.x = f2bf((v.x - mean) * rstd * gv.x + bv.x);
    ov.y = f2bf((v.y - mean) * rstd * gv.y + bv.y);
    ov.z = f2bf((v.z - mean) * rstd * gv.z + bv.z);
    ov.w = f2bf((v.w - mean) * rstd * gv.w + bv.w);
    *(ushort4*)(out + (size_t)row * DIM_ + t * 4) = ov;
}

// ---------------------------------------------------------------- 256² 2-phase GEMM
// BM=BN=256, BK=64, 512 thr = 8 waves (2M x 4N), wave tile 128x64 (MI=8, NI=4).
// Double-buffered LDS (128 KB), raw s_barrier + counted vmcnt(8): next tile's
// 8 gloads stay in flight across barriers. Final iter drains vmcnt(0) (no
// tile t+1 in flight). STAGE(t+2) issued only AFTER the barrier proving all
// waves finished reading buf[t&1] -> race-free overwrite.
// WMODE 2: fused QKV (q,k bf16 natural; v -> V^T). WMODE 1: bf16 out (+silu).
template<int WMODE, bool GROUPED, int ACT>
__global__ __launch_bounds__(512) void gemm2p(
    const u16* __restrict__ A, const u16* __restrict__ WT,
    const float* __restrict__ b0, const float* __restrict__ bk2, const float* __restrict__ bv2,
    u16* __restrict__ Cb, u16* __restrict__ Ckb, u16* __restrict__ vtb,
    int Nw, int K)
{
    __shared__ __attribute__((aligned(16))) char Ab[2][32768];
    __shared__ __attribute__((aligned(16))) char Bb[2][32768];

    int tid = threadIdx.x;
    int lane = tid & 63, w = tid >> 6;
    int wm = w >> 2, wn = w & 3;
    int g = lane >> 4, lq = lane & 15;

    long row0; int e = 0;
    const float* bias = b0;
    if (GROUPED) {
        int bb = (int)blockIdx.y >> 3; e = blockIdx.y & 7;
        row0 = (long)bb * SEQ + e * 256;
        bias += (size_t)e * Nw;
    } else row0 = (long)blockIdx.y * 256;

    int col0 = blockIdx.x * 256;
    int colL = col0, sel = 0;
    if (WMODE == 2) {
        sel = col0 >> 10; colL = col0 & 1023;
        if (sel == 1) bias = bk2; else if (sel == 2) bias = bv2;
    }

    const u16* Arow = A + (size_t)row0 * K;
    const u16* Brow = WT + (GROUPED ? ((size_t)e * Nw + col0) : (size_t)col0) * K;

    v4f acc[8][4];
    #pragma unroll
    for (int mi = 0; mi < 8; mi++)
        #pragma unroll
        for (int ni = 0; ni < 4; ni++) acc[mi][ni] = (v4f){0.f, 0.f, 0.f, 0.f};

    const int NT = K >> 6;

    auto STAGE = [&](int tt, int p) {
        int kb = tt * 64;
        #pragma unroll
        for (int i = 0; i < 4; i++) {
            int R0 = (i * 8 + w) * 8;
            int row = R0 + (lane >> 3);
            int sc = ((lane & 7) ^ (row & 7)) << 3;       // inverse-swizzled source
            gload16(Arow + (size_t)row * K + kb + sc, Ab[p] + R0 * 128);
            gload16(Brow + (size_t)row * K + kb + sc, Bb[p] + R0 * 128);
        }
    };

    STAGE(0, 0);
    STAGE(1, 1);

    for (int t = 0; t < NT; t++) {
        int par = t & 1;
        // per-wave: drain this tile's 8 loads; keep next tile's 8 in flight.
        // Final iter has no tile t+1 in flight -> must drain fully (race fix).
        if (t < NT - 1) asm volatile("s_waitcnt vmcnt(8)" ::: "memory");
        else            asm volatile("s_waitcnt vmcnt(0)" ::: "memory");
        __builtin_amdgcn_s_barrier();                     // all waves' tile-t rows in LDS
        __builtin_amdgcn_sched_barrier(0);
        #pragma unroll
        for (int kh = 0; kh < 2; kh++) {
            v8s af[8], bf[4];
            int slot = kh * 4 + g;
            #pragma unroll
            for (int mi = 0; mi < 8; mi++) {
                int row = wm * 128 + mi * 16 + lq;
                af[mi] = *(const v8s*)(Ab[par] + row * 128 + ((slot ^ (row & 7)) << 4));
            }
            #pragma unroll
            for (int ni = 0; ni < 4; ni++) {
                int rn = wn * 64 + ni * 16 + lq;
                bf[ni] = *(const v8s*)(Bb[par] + rn * 128 + ((slot ^ (rn & 7)) << 4));
            }
            __builtin_amdgcn_s_setprio(1);
            #pragma unroll
            for (int mi = 0; mi < 8; mi++)
                #pragma unroll
                for (int ni = 0; ni < 4; ni++)
                    acc[mi][ni] = __builtin_amdgcn_mfma_f32_16x16x32_bf16(
                        af[mi], bf[ni], acc[mi][ni], 0, 0, 0);
            __builtin_amdgcn_s_setprio(0);
        }
        __builtin_amdgcn_sched_barrier(0);                // pin reads before barrier
        __builtin_amdgcn_s_barrier();                     // all waves done reading buf[par]
        if (t + 2 < NT) STAGE(t + 2, par);                // safe overwrite
    }

    // epilogue. D frag: row=g*4+r, col=lq
    #pragma unroll
    for (int mi = 0; mi < 8; mi++) {
        int grow = wm * 128 + mi * 16 + g * 4;
        #pragma unroll
        for (int ni = 0; ni < 4; ni++) {
            int cL = colL + wn * 64 + ni * 16 + lq;
            float bb_ = bias[cL];
            v4f a = acc[mi][ni];
            if (WMODE == 2) {
                if (sel < 2) {
                    u16* dst = (sel == 0) ? Cb : Ckb;
                    #pragma unroll
                    for (int r = 0; r < 4; r++)
                        dst[(size_t)(row0 + grow + r) * 1024 + cL] = f2bf(a[r] + bb_);
                } else {
                    long token0 = row0 + grow;
                    int bb2 = (int)(token0 >> 11);
                    int ss  = (int)(token0 & 2047);
                    int hh = cL >> 6, dd = cL & 63;
                    ushort4 pv_;
                    pv_.x = f2bf(a[0] + bb_); pv_.y = f2bf(a[1] + bb_);
                    pv_.z = f2bf(a[2] + bb_); pv_.w = f2bf(a[3] + bb_);
                    *(ushort4*)(vtb + ((size_t)(bb2 * 16 + hh) * 64 + dd) * 2048 + ss) = pv_;
                }
            } else {
                #pragma unroll
                for (int r = 0; r < 4; r++) {
                    float val = a[r] + bb_;
                    if (ACT == 1) val = val / (1.0f + __expf(-val));
                    Cb[(size_t)(row0 + grow + r) * Nw + cL] = f2bf(val);
                }
            }
        }
    }
}

// ---------------------------------------------------------------- m97-style GEMM (o-proj, FFN2)
// WMODE 0 only: fp32 out + resid. BN=64.
template<int BN, bool GROUPED>
__global__ __launch_bounds__(256) void gemm_bf16(
    const u16* __restrict__ A, const u16* __restrict__ WT,
    const float* __restrict__ b0,
    const float* __restrict__ resid, float* __restrict__ Cf,
    int Nw, int K)
{
    constexpr int BM = 128;
    constexpr int MI = 4;
    constexpr int NI = BN / 32;
    __shared__ __attribute__((aligned(16))) char AsB[BM * 128];
    __shared__ __attribute__((aligned(16))) char BsB[BN * 128];

    int tid = threadIdx.x;
    int lane = tid & 63, w = tid >> 6;
    int wr = w >> 1, wc = w & 1;
    int g = lane >> 4, lq = lane & 15;

    long row0; int e = 0;
    const float* bias = b0;
    if (GROUPED) {
        int seg = blockIdx.y >> 1, mh = blockIdx.y & 1;
        int bb = seg >> 3; e = seg & 7;
        row0 = (long)bb * SEQ + e * 256 + mh * BM;
        bias += (size_t)e * Nw;
    } else row0 = (long)blockIdx.y * BM;

    int col0 = blockIdx.x * BN;
    const u16* Arow = A + (size_t)row0 * K;
    const u16* Brow = WT + (GROUPED ? ((size_t)e * Nw + col0) : (size_t)col0) * K;

    v4f acc[MI][NI];
    #pragma unroll
    for (int mi = 0; mi < MI; mi++)
        #pragma unroll
        for (int ni = 0; ni < NI; ni++) acc[mi][ni] = (v4f){0.f, 0.f, 0.f, 0.f};

    for (int kt = 0; kt < K; kt += 64) {
        #pragma unroll
        for (int i = 0; i < 4; i++) {
            int R0 = (i * 4 + w) * 8;
            int row = R0 + (lane >> 3);
            gload16(Arow + (size_t)row * K + kt + (((lane & 7) ^ (row & 7)) << 3),
                    AsB + R0 * 128);
        }
        #pragma unroll
        for (int i = 0; i < NI; i++) {
            int R0 = (i * 4 + w) * 8;
            int row = R0 + (lane >> 3);
            gload16(Brow + (size_t)row * K + kt + (((lane & 7) ^ (row & 7)) << 3),
                    BsB + R0 * 128);
        }
        __syncthreads();
        #pragma unroll
        for (int kk = 0; kk < 64; kk += 32) {
            v8s af[MI], bfv[NI];
            int slot = (kk >> 3) + g;
            #pragma unroll
            for (int mi = 0; mi < MI; mi++) {
                int row = wr * 64 + mi * 16 + lq;
                af[mi] = *(const v8s*)(AsB + row * 128 + ((slot ^ (row & 7)) << 4));
            }
            #pragma unroll
            for (int ni = 0; ni < NI; ni++) {
                int rn = wc * (BN / 2) + ni * 16 + lq;
                bfv[ni] = *(const v8s*)(BsB + rn * 128 + ((slot ^ (rn & 7)) << 4));
            }
            #pragma unroll
            for (int mi = 0; mi < MI; mi++)
                #pragma unroll
                for (int ni = 0; ni < NI; ni++)
                    acc[mi][ni] = __builtin_amdgcn_mfma_f32_16x16x32_bf16(
                        af[mi], bfv[ni], acc[mi][ni], 0, 0, 0);
        }
        __syncthreads();
    }

    #pragma unroll
    for (int mi = 0; mi < MI; mi++) {
        int grow = wr * 64 + mi * 16 + g * 4;
        #pragma unroll
        for (int ni = 0; ni < NI; ni++) {
            int cL = col0 + wc * (BN / 2) + ni * 16 + lq;
            float bb_ = bias[cL];
            v4f a = acc[mi][ni];
            #pragma unroll
            for (int r = 0; r < 4; r++) {
                size_t idx = (size_t)(row0 + grow + r) * Nw + cL;
                Cf[idx] = a[r] + bb_ + resid[idx];
            }
        }
    }
}

// ---------------------------------------------------------------- MFMA flash attention
__global__ __launch_bounds__(256) void attn_kernel(const u16* __restrict__ qb,
                                                   const u16* __restrict__ kb,
                                                   const u16* __restrict__ vtb,
                                                   u16* __restrict__ ob) {
    __shared__ __attribute__((aligned(16))) char Kl[8192];
    __shared__ __attribute__((aligned(16))) char Vl[8192];
    __shared__ __attribute__((aligned(16))) char Pl[4][4608];

    int tid = threadIdx.x;
    int lane = tid & 63, w = tid >> 6;
    int g = lane >> 4, lq = lane & 15;
    int h = blockIdx.y, bz = blockIdx.z;
    int q0 = blockIdx.x * 128 + w * 32;
    const size_t hb = (size_t)h * 64;

    v8s qfr[2][2];
    #pragma unroll
    for (int qi = 0; qi < 2; qi++)
        #pragma unroll
        for (int kkh = 0; kkh < 2; kkh++)
            qfr[qi][kkh] = *(const v8s*)(qb + ((size_t)(bz * SEQ + q0 + qi * 16 + lq)) * DIM_
                                         + hb + kkh * 32 + g * 8);

    v4f oacc[2][4];
    #pragma unroll
    for (int qi = 0; qi < 2; qi++)
        #pragma unroll
        for (int df = 0; df < 4; df++) oacc[qi][df] = (v4f){0.f, 0.f, 0.f, 0.f};
    float m_prev[2] = {-1e30f, -1e30f}, l_acc[2] = {0.f, 0.f};

    for (int kv = 0; kv < SEQ; kv += 64) {
        __syncthreads();
        #pragma unroll
        for (int i = 0; i < 2; i++) {
            int beta = (i * 4 + w) * 1024 + lane * 16;
            int row  = beta >> 7;
            int sc   = ((lane & 7) ^ (row & 7)) << 3;
            gload16(kb + ((size_t)(bz * SEQ + kv + row)) * DIM_ + hb + sc,
                    Kl + (i * 4 + w) * 1024);
            gload16(vtb + ((size_t)((bz * 16 + h) * 64 + row)) * 2048 + kv + sc,
                    Vl + (i * 4 + w) * 1024);
        }
        __syncthreads();

        v4f sa[4][2];
        #pragma unroll
        for (int cf = 0; cf < 4; cf++)
            #pragma unroll
            for (int qi = 0; qi < 2; qi++) sa[cf][qi] = (v4f){0.f, 0.f, 0.f, 0.f};
        #pragma unroll
        for (int kkh = 0; kkh < 2; kkh++) {
            v8s kf[4];
            int slot = kkh * 4 + g;
            #pragma unroll
            for (int cf = 0; cf < 4; cf++) {
                int row = cf * 16 + lq;
                kf[cf] = *(const v8s*)(Kl + row * 128 + ((slot ^ (row & 7)) << 4));
            }
            #pragma unroll
            for (int cf = 0; cf < 4; cf++)
                #pragma unroll
                for (int qi = 0; qi < 2; qi++)
                    sa[cf][qi] = __builtin_amdgcn_mfma_f32_16x16x32_bf16(
                        kf[cf], qfr[qi][kkh], sa[cf][qi], 0, 0, 0);
        }

        #pragma unroll
        for (int qi = 0; qi < 2; qi++) {
            float mx = -1e30f;
            #pragma unroll
            for (int cf = 0; cf < 4; cf++)
                #pragma unroll
                for (int r = 0; r < 4; r++) mx = fmaxf(mx, sa[cf][qi][r]);
            mx = fmaxf(mx, __shfl_xor(mx, 16));
            mx = fmaxf(mx, __shfl_xor(mx, 32));
            float rm = mx * 0.125f;
            if (__any(rm - m_prev[qi] > 8.0f)) {
                float mnew = fmaxf(m_prev[qi], rm);
                float corr = __expf(m_prev[qi] - mnew);
                m_prev[qi] = mnew;
                l_acc[qi] *= corr;
                #pragma unroll
                for (int r = 0; r < 4; r++) {
                    float cr = __shfl(corr, (lane & 48) | (g * 4 + r));
                    #pragma unroll
                    for (int df = 0; df < 4; df++) oacc[qi][df][r] *= cr;
                }
            }
            float rs = 0.f;
            float ps[4][4];
            #pragma unroll
            for (int cf = 0; cf < 4; cf++)
                #pragma unroll
                for (int r = 0; r < 4; r++) {
                    float p = __expf(sa[cf][qi][r] * 0.125f - m_prev[qi]);
                    ps[cf][r] = p; rs += p;
                }
            rs += __shfl_xor(rs, 16);
            rs += __shfl_xor(rs, 32);
            l_acc[qi] += rs;
            #pragma unroll
            for (int cf = 0; cf < 4; cf++) {
                ushort4 pw;
                pw.x = f2bf(ps[cf][0]); pw.y = f2bf(ps[cf][1]);
                pw.z = f2bf(ps[cf][2]); pw.w = f2bf(ps[cf][3]);
                *(ushort4*)(Pl[w] + (qi * 16 + lq) * 144 + (cf * 16 + g * 4) * 2) = pw;
            }
        }
        asm volatile("s_waitcnt lgkmcnt(0)" ::: "memory");
        __builtin_amdgcn_sched_barrier(0);

        #pragma unroll
        for (int kkh = 0; kkh < 2; kkh++) {
            v8s pa[2], vf[4];
            int slot = kkh * 4 + g;
            #pragma unroll
            for (int qi = 0; qi < 2; qi++)
                pa[qi] = *(const v8s*)(Pl[w] + (qi * 16 + lq) * 144 + kkh * 64 + g * 16);
            #pragma unroll
            for (int df = 0; df < 4; df++) {
                int row = df * 16 + lq;
                vf[df] = *(const v8s*)(Vl + row * 128 + ((slot ^ (row & 7)) << 4));
            }
            #pragma unroll
            for (int qi = 0; qi < 2; qi++)
                #pragma unroll
                for (int df = 0; df < 4; df++)
                    oacc[qi][df] = __builtin_amdgcn_mfma_f32_16x16x32_bf16(
                        pa[qi], vf[df], oacc[qi][df], 0, 0, 0);
        }
    }

    #pragma unroll
    for (int qi = 0; qi < 2; qi++) {
        float inv = 1.0f / l_acc[qi];
        #pragma unroll
        for (int r = 0; r < 4; r++) {
            float ivr = __shfl(inv, (lane & 48) | (g * 4 + r));
            size_t rowi = (size_t)(bz * SEQ + q0 + qi * 16 + g * 4 + r) * DIM_ + hb;
            #pragma unroll
            for (int df = 0; df < 4; df++)
                ob[rowi + df * 16 + lq] = f2bf(oacc[qi][df][r] * ivr);
        }
    }
}

// ---------------------------------------------------------------- launcher
extern "C" void kernel_launch(void* const* d_in, const int* in_sizes, int n_in,
                              void* d_out, int out_size, void* d_ws, size_t ws_size,
                              hipStream_t stream) {
    const float* x     = (const float*)d_in[0];
    const float* ln1_g = (const float*)d_in[1];
    const float* ln1_b = (const float*)d_in[2];
    const float* ln2_g = (const float*)d_in[3];
    const float* ln2_b = (const float*)d_in[4];
    const float* wq = (const float*)d_in[5];  const float* bq = (const float*)d_in[6];
    const float* wk = (const float*)d_in[7];  const float* bk = (const float*)d_in[8];
    const float* wv = (const float*)d_in[9];  const float* bv = (const float*)d_in[10];
    const float* wo = (const float*)d_in[11]; const float* bo = (const float*)d_in[12];
    const float* w1 = (const float*)d_in[13]; const float* b1 = (const float*)d_in[14];
    const float* w2 = (const float*)d_in[15]; const float* b2 = (const float*)d_in[16];

    char* wsb = (char*)d_ws;
    const size_t MB = 1024 * 1024;
    u16*   h1   = (u16*)(wsb + 0 * MB);     // 8 MB ; ob after attn
    u16*   qbf  = (u16*)(wsb + 8 * MB);     // 8 MB ; h2 after attn
    u16*   kbf  = (u16*)(wsb + 16 * MB);    // 8 MB
    u16*   vt   = (u16*)(wsb + 24 * MB);    // 8 MB  V^T [2][16][64][2048]
    float* x2   = (float*)(wsb + 32 * MB);  // 16 MB fp32
    u16*   wqkvoT = (u16*)(wsb + 48 * MB);  // 8 MB  [4][1024][1024]
    u16*   mid  = (u16*)(wsb + 48 * MB);    // 32 MB (after o-proj)
    u16*   w1T  = (u16*)(wsb + 80 * MB);    // 64 MB [8][4096][1024]
    u16*   w2T  = (u16*)(wsb + 80 * MB);    // 64 MB [8][1024][4096] (after FFN1)
    u16*   ob   = h1;
    u16*   h2   = qbf;
    float* outp = (float*)d_out;

    conv_t<true ><<<dim3(16, 16, 4), 256, 0, stream>>>(wq, wk, wv, wo, wqkvoT, 1024, 1024);
    conv_t<false><<<dim3(64, 16, 8), 256, 0, stream>>>(w1, nullptr, nullptr, nullptr, w1T, 1024, 4096);

    ln_kernel<<<4096, 256, 0, stream>>>(x, ln1_g, ln1_b, h1);

    // fused QKV on 2-phase 256² engine: N=3072 (12 col-blocks), M=4096 (16)
    gemm2p<2, false, 0><<<dim3(12, 16), 512, 0, stream>>>(
        h1, wqkvoT, bq, bk, bv, qbf, kbf, vt, 1024, 1024);

    attn_kernel<<<dim3(16, 16, 2), 256, 0, stream>>>(qbf, kbf, vt, ob);

    gemm_bf16<64, false><<<dim3(16, 32), 256, 0, stream>>>(
        ob, wqkvoT + (size_t)3 * 1024 * 1024, bo, x, x2, 1024, 1024);

    ln_kernel<<<4096, 256, 0, stream>>>(x2, ln2_g, ln2_b, h2);

    // FFN1 on 2-phase 256² engine: grouped, 16 segs x 16 col-blocks
    gemm2p<1, true, 1><<<dim3(16, 16), 512, 0, stream>>>(
        h2, w1T, b1, nullptr, nullptr, mid, nullptr, nullptr, 4096, 1024);

    conv_t<false><<<dim3(16, 64, 8), 256, 0, stream>>>(w2, nullptr, nullptr, nullptr, w2T, 4096, 1024);

    gemm_bf16<64, true><<<dim3(16, 32), 256, 0, stream>>>(
        mid, w2T, b2, x2, outp, 1024, 4096);
}